// Round 7
// baseline (7999.873 us; speedup 1.0000x reference)
//
#include <hip/hip_runtime.h>
#include <stdint.h>
#include <math.h>

// Problem dims
#define SEQL 70
#define BAT 80
#define EMBD 400
#define HIDD 1150
#define GATES 4600        // 4*HIDD
#define NTOKV 33278
#define MALL 5600         // SEQL*BAT
// Padded dims (K multiple of 32, N multiple of 128)
#define KH 1152
#define KE 416
#define N4P 4608
#define NVP 33280
// persistent LSTM kernel
#define NBLK 72
#define WPAD 1160         // LDS row stride for Whh slice (bank-conflict-free)

typedef __bf16 bf16;
typedef bf16 bf16x8 __attribute__((ext_vector_type(8)));
typedef float f32x4 __attribute__((ext_vector_type(4)));

__device__ __forceinline__ float ld_in(const void* p, size_t i, int f32w) {
    return f32w ? ((const float*)p)[i] : (float)((const bf16*)p)[i];
}
__device__ __forceinline__ float clampdiag(float v) {
    return fminf(fmaxf(v, -30000.f), 30000.f);
}

// sc0 sc1 store: write-through to the device coherence point (L3).
__device__ __forceinline__ void store_h_sc1(bf16* addr, uint32_t bits) {
    asm volatile("global_store_short %0, %1, off sc0 sc1"
                 :: "v"(addr), "v"(bits) : "memory");
}

// ---------------------------------------------------------------------------
// Input-dtype detector (f32 world vs bf16 world) — validated round 3.
// ---------------------------------------------------------------------------
__global__ void detect_dtype(const void* __restrict__ emb, int* __restrict__ flag)
{
    __shared__ int fails;
    if (threadIdx.x == 0) fails = 0;
    __syncthreads();
    const uint32_t* w = (const uint32_t*)emb;
    int f = 0;
    for (int i = threadIdx.x; i < 1024; i += blockDim.x) {
        uint32_t h0 = w[i] & 0xFFFFu;
        uint32_t e0 = (h0 >> 7) & 0xFFu;
        if (e0 > 122u) f++;
    }
    atomicAdd(&fails, f);
    __syncthreads();
    if (threadIdx.x == 0) *flag = (fails > 100) ? 1 : 0;
}

// ---------------------------------------------------------------------------
// NT GEMM (unchanged from r6): band swizzle, stride-40 LDS.
// ---------------------------------------------------------------------------
__global__ __launch_bounds__(256)
void gemm_bt(const bf16* __restrict__ A, int lda,
             const bf16* __restrict__ Bw, int ldb,
             const float* __restrict__ bias,
             void* __restrict__ Cp, long long ldc,
             int M, int K, int Nout, int outMode, const int* __restrict__ dflag,
             int gx, int gy)
{
    __shared__ __align__(16) bf16 As[128 * 40];
    __shared__ __align__(16) bf16 Bs[128 * 40];
    const int f32w = *dflag;
    const int tid  = threadIdx.x;
    const int lane = tid & 63;
    const int w    = tid >> 6;

    const int Wb = 32;
    int id = blockIdx.x;
    int fullb = gx / Wb, tw = gx - fullb * Wb;
    int bx, by;
    if (id < fullb * Wb * gy) {
        int band = id / (Wb * gy), wi = id % (Wb * gy);
        bx = band * Wb + wi % Wb;
        by = wi / Wb;
    } else {
        int wi = id - fullb * Wb * gy;
        bx = fullb * Wb + wi % tw;
        by = wi / tw;
    }
    const int bm = by * 128;
    const int bn = bx * 128;

    const int r    = tid >> 1;
    const int kq   = (tid & 1) * 16;
    const int arow = min(bm + r, M - 1);
    const bf16* ga = A  + (size_t)arow * lda + kq;
    const bf16* gb = Bw + (size_t)(bn + r) * ldb + kq;
    const int wm = (w >> 1) * 64;
    const int wn = (w & 1) * 64;
    const int lr = lane & 15;
    const int lk = (lane >> 4) * 8;

    f32x4 acc[4][4] = {};

    for (int k0 = 0; k0 < K; k0 += 32) {
        bf16x8 va0 = *(const bf16x8*)(ga + k0);
        bf16x8 va1 = *(const bf16x8*)(ga + k0 + 8);
        bf16x8 vb0 = *(const bf16x8*)(gb + k0);
        bf16x8 vb1 = *(const bf16x8*)(gb + k0 + 8);
        __syncthreads();
        *(bf16x8*)&As[r * 40 + kq]     = va0;
        *(bf16x8*)&As[r * 40 + kq + 8] = va1;
        *(bf16x8*)&Bs[r * 40 + kq]     = vb0;
        *(bf16x8*)&Bs[r * 40 + kq + 8] = vb1;
        __syncthreads();
        bf16x8 af[4], bfv[4];
#pragma unroll
        for (int mi = 0; mi < 4; ++mi)
            af[mi] = *(const bf16x8*)&As[(wm + mi * 16 + lr) * 40 + lk];
#pragma unroll
        for (int ni = 0; ni < 4; ++ni)
            bfv[ni] = *(const bf16x8*)&Bs[(wn + ni * 16 + lr) * 40 + lk];
#pragma unroll
        for (int mi = 0; mi < 4; ++mi)
#pragma unroll
            for (int ni = 0; ni < 4; ++ni)
                acc[mi][ni] = __builtin_amdgcn_mfma_f32_16x16x32_bf16(
                    af[mi], bfv[ni], acc[mi][ni], 0, 0, 0);
    }

#pragma unroll
    for (int mi = 0; mi < 4; ++mi)
#pragma unroll
        for (int ni = 0; ni < 4; ++ni) {
            int n = bn + wn + ni * 16 + lr;
            if (n >= Nout) continue;
            float bv = bias[n];
#pragma unroll
            for (int rr = 0; rr < 4; ++rr) {
                int m = bm + wm + mi * 16 + (lane >> 4) * 4 + rr;
                if (m < M) {
                    float v = clampdiag(acc[mi][ni][rr] + bv);
                    size_t idx = (size_t)m * ldc + n;
                    if (outMode == 0)      ((float*)Cp)[idx] = v;
                    else if (outMode == 1) ((bf16*)Cp)[idx] = (bf16)v;
                    else {
                        if (f32w) ((float*)Cp)[idx] = v;
                        else      ((bf16*)Cp)[idx] = (bf16)v;
                    }
                }
            }
        }
}

// ---------------------------------------------------------------------------
// Grid barrier v2: plain atomic arrival + NON-SERIALIZING sc0sc1 load poll
// (bypasses L2 -> reads coherence point; no RMW queueing across 72 pollers).
// ---------------------------------------------------------------------------
__device__ __forceinline__ void gridbar(int* ctr, int target)
{
    __syncthreads();
    if (threadIdx.x == 0) {
        atomicAdd(ctr, 1);
        int v;
        do {
            asm volatile("global_load_dword %0, %1, off sc0 sc1\n\t"
                         "s_waitcnt vmcnt(0)"
                         : "=v"(v) : "v"(ctr) : "memory");
        } while (v < target);
    }
    __syncthreads();
    asm volatile("" ::: "memory");
}

template<typename GT>
__device__ __forceinline__ void load_gslice(const GT* __restrict__ G, int t,
                                            int cb, int jc, float* dst)
{
    const GT* gq = G + (size_t)t * BAT * N4P;
#pragma unroll
    for (int Q = 0; Q < 4; ++Q) {
        const GT* g = gq + (size_t)(Q * 20 + cb) * N4P + jc;
        dst[Q * 4 + 0] = (float)g[0];
        dst[Q * 4 + 1] = (float)g[HIDD];
        dst[Q * 4 + 2] = (float)g[2 * HIDD];
        dst[Q * 4 + 3] = (float)g[3 * HIDD];
    }
}

// ---------------------------------------------------------------------------
// Persistent per-layer LSTM with ablation variants:
//   VAR==0 baseline; VAR==1 double barrier; VAR==2 double MFMA+H-load phase.
// All three produce identical (correct) results.
// ---------------------------------------------------------------------------
template<int VAR, typename GT>
__global__ __launch_bounds__(512, 2)
void lstm_layer(const bf16* __restrict__ Whh,
                const GT* __restrict__ G,
                const bf16* __restrict__ H0,
                float* __restrict__ Cst,
                bf16* __restrict__ HA,
                int* __restrict__ ctr)
{
    __shared__ __align__(16) bf16 Wl[64 * WPAD];   // 148,480 B
    __shared__ float pl[4][2][20][16];             // 10,240 B
    const int tid  = threadIdx.x;
    const int lane = tid & 63;
    const int wid  = tid >> 6;
    const int s    = wid >> 1;
    const int kh   = wid & 1;
    const int q    = lane >> 4;
    const int lr   = lane & 15;
    const int n0   = blockIdx.x * 16;

    for (int i = tid; i < 64 * (KH / 8); i += 512) {
        int rrow = i / (KH / 8), c8 = i % (KH / 8);
        int ss = rrow >> 4, ll = rrow & 15;
        int gj = min(n0 + ll, HIDD - 1);
        bf16x8 v = *(const bf16x8*)(Whh + (size_t)(ss * HIDD + gj) * KH + c8 * 8);
        *(bf16x8*)&Wl[rrow * WPAD + c8 * 8] = v;
    }
    __syncthreads();

    const int cb = tid >> 4, cj = tid & 15;
    const int jc = n0 + cj;
    const bool cons = (tid < 320) && (jc < HIDD);
    float creg[4];
    if (cons) {
#pragma unroll
        for (int Q = 0; Q < 4; ++Q)
            creg[Q] = Cst[(size_t)(Q * 20 + cb) * KH + jc];
    }

    float gp[16], gnx[16];
    if (cons) load_gslice(G, 0, cb, jc, gp);

    const bf16* wlp = &Wl[(s * 16 + lr) * WPAD + kh * 576 + q * 8];

    for (int t = 0; t < SEQL; ++t) {
        const bf16* Hin = t ? (HA + (size_t)(t - 1) * BAT * KH) : H0;
        bf16*       HAt = HA + (size_t)t * BAT * KH;

        if (cons && (t + 1 < SEQL)) load_gslice(G, t + 1, cb, jc, gnx);

        const bf16* hbp = Hin + (size_t)lr * KH + kh * 576 + q * 8;

        if constexpr (VAR == 2) {
            // dummy pass: same H loads (obfuscated pointer, no CSE) + MFMAs
            const bf16* hbp2 = hbp;
            asm volatile("" : "+v"(hbp2));
            f32x4 accD[5] = {};
#pragma unroll
            for (int kt = 0; kt < 18; ++kt) {
                bf16x8 bfrag = *(const bf16x8*)(wlp + kt * 32);
#pragma unroll
                for (int mi = 0; mi < 5; ++mi) {
                    bf16x8 afrag = *(const bf16x8*)(hbp2 + (size_t)mi * 16 * KH + kt * 32);
                    accD[mi] = __builtin_amdgcn_mfma_f32_16x16x32_bf16(afrag, bfrag, accD[mi], 0, 0, 0);
                }
            }
#pragma unroll
            for (int mi = 0; mi < 5; ++mi)
                asm volatile("" :: "v"(accD[mi][0]), "v"(accD[mi][1]),
                                   "v"(accD[mi][2]), "v"(accD[mi][3]));
        }

        f32x4 acc[5] = {};
#pragma unroll
        for (int kt = 0; kt < 18; ++kt) {
            bf16x8 bfrag = *(const bf16x8*)(wlp + kt * 32);
#pragma unroll
            for (int mi = 0; mi < 5; ++mi) {
                bf16x8 afrag = *(const bf16x8*)(hbp + (size_t)mi * 16 * KH + kt * 32);
                acc[mi] = __builtin_amdgcn_mfma_f32_16x16x32_bf16(afrag, bfrag, acc[mi], 0, 0, 0);
            }
        }

#pragma unroll
        for (int Q = 0; Q < 4; ++Q) {
            const int b0 = Q * 20;
#pragma unroll
            for (int mi = 0; mi < 5; ++mi)
#pragma unroll
                for (int rr = 0; rr < 4; ++rr) {
                    int m = mi * 16 + q * 4 + rr;
                    if (m >= b0 && m < b0 + 20) pl[s][kh][m - b0][lr] = acc[mi][rr];
                }
            __syncthreads();
            if (cons) {
                float pi = pl[0][0][cb][cj] + pl[0][1][cb][cj] + gp[Q * 4 + 0];
                float pf = pl[1][0][cb][cj] + pl[1][1][cb][cj] + gp[Q * 4 + 1];
                float po = pl[2][0][cb][cj] + pl[2][1][cb][cj] + gp[Q * 4 + 2];
                float pg = pl[3][0][cb][cj] + pl[3][1][cb][cj] + gp[Q * 4 + 3];
                float ii = 1.f / (1.f + expf(-pi));
                float ff = 1.f / (1.f + expf(-pf));
                float oo = 1.f / (1.f + expf(-po));
                float gg = tanhf(pg);
                float cn = ff * creg[Q] + ii * gg;
                creg[Q] = cn;
                bf16 hv = (bf16)(oo * tanhf(cn));
                uint32_t bits = (uint32_t)__builtin_bit_cast(unsigned short, hv);
                store_h_sc1(HAt + (size_t)(b0 + cb) * KH + jc, bits);
            }
            __syncthreads();
        }

        if (t < SEQL - 1) {
            asm volatile("s_waitcnt vmcnt(0)" ::: "memory");
            if constexpr (VAR == 1) {
                gridbar(ctr, NBLK * (2 * t + 1));
                gridbar(ctr, NBLK * (2 * t + 2));
            } else {
                gridbar(ctr, NBLK * (t + 1));
            }
        }
#pragma unroll
        for (int i = 0; i < 16; ++i) gp[i] = gnx[i];
    }

    if (cons) {
#pragma unroll
        for (int Q = 0; Q < 4; ++Q)
            Cst[(size_t)(Q * 20 + cb) * KH + jc] = creg[Q];
    }
}

__global__ void bar_reset(int* ctr) { if (threadIdx.x == 0) *ctr = 0; }

// ---------------------------------------------------------------------------
// Prep kernels (dual-dtype via dflag) — unchanged.
// ---------------------------------------------------------------------------
__global__ void pad_weight(const void* __restrict__ src, int N, int K,
                           bf16* __restrict__ dst, int Np, int Kp,
                           const int* __restrict__ dflag)
{
    const int f32w = *dflag;
    size_t total = (size_t)Np * Kp;
    for (size_t i = (size_t)blockIdx.x * blockDim.x + threadIdx.x; i < total;
         i += (size_t)gridDim.x * blockDim.x) {
        int n = (int)(i / Kp), k = (int)(i % Kp);
        dst[i] = (n < N && k < K) ? (bf16)ld_in(src, (size_t)n * K + k, f32w)
                                  : (bf16)0.f;
    }
}

__global__ void combine_bias(const void* a, const void* b, float* o, int n, int np,
                             const int* __restrict__ dflag)
{
    const int f32w = *dflag;
    int i = blockIdx.x * blockDim.x + threadIdx.x;
    if (i < np) o[i] = (i < n) ? ld_in(a, i, f32w) + ld_in(b, i, f32w) : 0.f;
}

__global__ void cvt_bias(const void* a, float* o, int n, int np,
                         const int* __restrict__ dflag)
{
    const int f32w = *dflag;
    int i = blockIdx.x * blockDim.x + threadIdx.x;
    if (i < np) o[i] = (i < n) ? ld_in(a, i, f32w) : 0.f;
}

__global__ void embed_gather(const int* __restrict__ x, const void* __restrict__ emb,
                             bf16* __restrict__ XE, const int* __restrict__ dflag)
{
    const int f32w = *dflag;
    int row = blockIdx.x;
    int xi  = x[row];
    for (int e = threadIdx.x; e < KE; e += blockDim.x)
        XE[(size_t)row * KE + e] =
            (e < EMBD) ? (bf16)ld_in(emb, (size_t)xi * EMBD + e, f32w) : (bf16)0.f;
}

__global__ void zero_ha_pad(bf16* HA)
{
    int i = blockIdx.x * blockDim.x + threadIdx.x;
    if (i < MALL * 2) HA[(size_t)(i >> 1) * KH + HIDD + (i & 1)] = (bf16)0.f;
}

__global__ void init_state(const void* __restrict__ h0, const void* __restrict__ c0,
                           size_t lofs, bf16* Hb0, float* Cst,
                           const int* __restrict__ dflag)
{
    const int f32w = *dflag;
    int i = blockIdx.x * blockDim.x + threadIdx.x;
    if (i >= BAT * KH) return;
    int b = i / KH, j = i % KH;
    if (j < HIDD) {
        Hb0[i] = (bf16)ld_in(h0, lofs + (size_t)b * HIDD + j, f32w);
        Cst[i] = ld_in(c0, lofs + (size_t)b * HIDD + j, f32w);
    } else {
        Hb0[i] = (bf16)0.f;
        Cst[i] = 0.f;
    }
}

__global__ void write_tail(const bf16* __restrict__ Hfin, const float* __restrict__ Cfin,
                           void* __restrict__ outBase, size_t hOfs, size_t cOfs,
                           const int* __restrict__ dflag)
{
    const int f32w = *dflag;
    int i = blockIdx.x * blockDim.x + threadIdx.x;
    if (i >= BAT * HIDD) return;
    int b = i / HIDD, j = i % HIDD;
    float hv = clampdiag((float)Hfin[b * KH + j]);
    float cv = clampdiag(Cfin[b * KH + j]);
    if (f32w) {
        ((float*)outBase)[hOfs + i] = hv;
        ((float*)outBase)[cOfs + i] = cv;
    } else {
        ((bf16*)outBase)[hOfs + i] = (bf16)hv;
        ((bf16*)outBase)[cOfs + i] = (bf16)cv;
    }
}

__global__ void sentinel_kernel(void* out, float v, const int* __restrict__ dflag)
{
    if (blockIdx.x == 0 && threadIdx.x == 0) {
        if (*dflag) ((float*)out)[0] = v;
        else        ((bf16*)out)[0] = (bf16)v;
    }
}

// ---------------------------------------------------------------------------
extern "C" void kernel_launch(void* const* d_in, const int* in_sizes, int n_in,
                              void* d_out, int out_size, void* d_ws, size_t ws_size,
                              hipStream_t stream)
{
    const int*  x    = (const int*)d_in[0];
    const void* h0   = d_in[1];
    const void* c0   = d_in[2];
    const void* emb  = d_in[3];
    const void* wih[3] = {d_in[4], d_in[8],  d_in[12]};
    const void* bih[3] = {d_in[5], d_in[9],  d_in[13]};
    const void* whh[3] = {d_in[6], d_in[10], d_in[14]};
    const void* bhh[3] = {d_in[7], d_in[11], d_in[15]};
    const void* wdec = d_in[16];
    const void* bdec = d_in[17];
    const size_t DEC = (size_t)MALL * NTOKV;
    (void)in_sizes; (void)n_in; (void)out_size;

    auto al = [](size_t v) { return (v + 255) & ~(size_t)255; };
    const size_t wdecB = al((size_t)NVP * KH * 2);
    auto plan = [&](bool gbf, size_t* offs) -> size_t {
        size_t off = 0;
        auto carve = [&](size_t b) { size_t p = off; off += al(b); return p; };
        offs[0] = carve((size_t)MALL * N4P * (gbf ? 2 : 4));
        offs[1] = carve((size_t)MALL * KE * 2);
        offs[2] = carve((size_t)N4P * KH * 2);
        offs[3] = carve((size_t)N4P * KH * 2);
        if (off < wdecB) off = wdecB;
        offs[4] = carve((size_t)MALL * KH * 2);
        offs[5] = carve((size_t)N4P * 4);
        offs[6] = carve((size_t)NVP * 4);
        offs[7] = carve((size_t)BAT * KH * 2);
        offs[8] = carve((size_t)BAT * KH * 4);
        offs[9] = carve(256);
        return off;
    };
    size_t offs[10];
    size_t needA = plan(false, offs);
    size_t needB = plan(true, offs);
    bool gbf16;
    if (ws_size >= needA)      { gbf16 = false; plan(false, offs); }
    else if (ws_size >= needB) { gbf16 = true;  plan(true,  offs); }
    else {
        int* dflag = (int*)d_ws;
        detect_dtype<<<1, 256, 0, stream>>>(emb, dflag);
        float mb = (float)(ws_size >> 20);
        if (mb > 20000.f) mb = 20000.f;
        sentinel_kernel<<<1, 64, 0, stream>>>(d_out, 700.f + mb, dflag);
        return;
    }

    char* ws = (char*)d_ws;
    void* G      = ws + offs[0];
    bf16* XE     = (bf16*)(ws + offs[1]);
    bf16* WihP   = (bf16*)(ws + offs[2]);
    bf16* WhhP   = (bf16*)(ws + offs[3]);
    bf16* WdecP  = (bf16*)(ws + 0);
    bf16* HA     = (bf16*)(ws + offs[4]);
    float* bc    = (float*)(ws + offs[5]);
    float* bd    = (float*)(ws + offs[6]);
    bf16* H0buf  = (bf16*)(ws + offs[7]);
    float* Cst   = (float*)(ws + offs[8]);
    int*  dflag  = (int*)(ws + offs[9]);
    int*  barctr = (int*)(ws + offs[9] + 128);

    detect_dtype<<<1, 256, 0, stream>>>(emb, dflag);
    embed_gather<<<MALL, 128, 0, stream>>>(x, emb, XE, dflag);
    zero_ha_pad<<<(MALL * 2 + 255) / 256, 256, 0, stream>>>(HA);

    for (int l = 0; l < 3; ++l) {
        int kin = (l == 0) ? KE : KH;
        int Kin = (l == 0) ? EMBD : HIDD;
        pad_weight<<<2048, 256, 0, stream>>>(wih[l], GATES, Kin, WihP, N4P, kin, dflag);
        pad_weight<<<2048, 256, 0, stream>>>(whh[l], GATES, HIDD, WhhP, N4P, KH, dflag);
        combine_bias<<<(N4P + 255) / 256, 256, 0, stream>>>(bih[l], bhh[l], bc, GATES, N4P, dflag);
        init_state<<<(BAT * KH + 255) / 256, 256, 0, stream>>>(
            h0, c0, (size_t)l * BAT * HIDD, H0buf, Cst, dflag);
        bar_reset<<<1, 64, 0, stream>>>(barctr);
        const bf16* Ain = (l == 0) ? XE : HA;
        {
            int gx = N4P / 128, gy = (MALL + 127) / 128;
            gemm_bt<<<gx * gy, 256, 0, stream>>>(
                Ain, kin, WihP, kin, bc, G, N4P, MALL, kin, N4P,
                gbf16 ? 1 : 0, dflag, gx, gy);
        }
        if (gbf16) {
            if (l == 0)      lstm_layer<0, bf16><<<NBLK, 512, 0, stream>>>(WhhP, (const bf16*)G, H0buf, Cst, HA, barctr);
            else if (l == 1) lstm_layer<1, bf16><<<NBLK, 512, 0, stream>>>(WhhP, (const bf16*)G, H0buf, Cst, HA, barctr);
            else             lstm_layer<2, bf16><<<NBLK, 512, 0, stream>>>(WhhP, (const bf16*)G, H0buf, Cst, HA, barctr);
        } else {
            if (l == 0)      lstm_layer<0, float><<<NBLK, 512, 0, stream>>>(WhhP, (const float*)G, H0buf, Cst, HA, barctr);
            else if (l == 1) lstm_layer<1, float><<<NBLK, 512, 0, stream>>>(WhhP, (const float*)G, H0buf, Cst, HA, barctr);
            else             lstm_layer<2, float><<<NBLK, 512, 0, stream>>>(WhhP, (const float*)G, H0buf, Cst, HA, barctr);
        }
        write_tail<<<(BAT * HIDD + 255) / 256, 256, 0, stream>>>(
            HA + (size_t)(SEQL - 1) * BAT * KH, Cst, d_out,
            DEC + (size_t)l * BAT * HIDD,
            DEC + (size_t)3 * BAT * HIDD + (size_t)l * BAT * HIDD, dflag);
    }

    pad_weight<<<4096, 256, 0, stream>>>(wdec, NTOKV, HIDD, WdecP, NVP, KH, dflag);
    cvt_bias<<<(NVP + 255) / 256, 256, 0, stream>>>(bdec, bd, NTOKV, NVP, dflag);
    {
        int gx = NVP / 128, gy = (MALL + 127) / 128;
        gemm_bt<<<gx * gy, 256, 0, stream>>>(
            HA, KH, WdecP, KH, bd, d_out, NTOKV, MALL, KH, NTOKV, 2, dflag, gx, gy);
    }
}

// Round 8
// 4257.541 us; speedup vs baseline: 1.8790x; 1.8790x over previous
//
#include <hip/hip_runtime.h>
#include <stdint.h>
#include <math.h>

// Problem dims
#define SEQL 70
#define BAT 80
#define EMBD 400
#define HIDD 1150
#define GATES 4600        // 4*HIDD
#define NTOKV 33278
#define MALL 5600         // SEQL*BAT
// Padded dims (K multiple of 32, N multiple of 128)
#define KH 1152
#define KE 416
#define N4P 4608
#define NVP 33280
// persistent LSTM kernel
#define NBLK 72

typedef __bf16 bf16;
typedef bf16 bf16x8 __attribute__((ext_vector_type(8)));
typedef float f32x4 __attribute__((ext_vector_type(4)));

__device__ __forceinline__ float ld_in(const void* p, size_t i, int f32w) {
    return f32w ? ((const float*)p)[i] : (float)((const bf16*)p)[i];
}
__device__ __forceinline__ float clampdiag(float v) {
    return fminf(fmaxf(v, -30000.f), 30000.f);
}

// sc0 sc1 store: write-through to the device coherence point (L3).
__device__ __forceinline__ void store_h_sc1(bf16* addr, uint32_t bits) {
    asm volatile("global_store_short %0, %1, off sc0 sc1"
                 :: "v"(addr), "v"(bits) : "memory");
}

// ---------------------------------------------------------------------------
// Input-dtype detector (f32 world vs bf16 world) — validated round 3.
// ---------------------------------------------------------------------------
__global__ void detect_dtype(const void* __restrict__ emb, int* __restrict__ flag)
{
    __shared__ int fails;
    if (threadIdx.x == 0) fails = 0;
    __syncthreads();
    const uint32_t* w = (const uint32_t*)emb;
    int f = 0;
    for (int i = threadIdx.x; i < 1024; i += blockDim.x) {
        uint32_t h0 = w[i] & 0xFFFFu;
        uint32_t e0 = (h0 >> 7) & 0xFFu;
        if (e0 > 122u) f++;
    }
    atomicAdd(&fails, f);
    __syncthreads();
    if (threadIdx.x == 0) *flag = (fails > 100) ? 1 : 0;
}

// ---------------------------------------------------------------------------
// NT GEMM (unchanged): band swizzle, stride-40 LDS.
// ---------------------------------------------------------------------------
__global__ __launch_bounds__(256)
void gemm_bt(const bf16* __restrict__ A, int lda,
             const bf16* __restrict__ Bw, int ldb,
             const float* __restrict__ bias,
             void* __restrict__ Cp, long long ldc,
             int M, int K, int Nout, int outMode, const int* __restrict__ dflag,
             int gx, int gy)
{
    __shared__ __align__(16) bf16 As[128 * 40];
    __shared__ __align__(16) bf16 Bs[128 * 40];
    const int f32w = *dflag;
    const int tid  = threadIdx.x;
    const int lane = tid & 63;
    const int w    = tid >> 6;

    const int Wb = 32;
    int id = blockIdx.x;
    int fullb = gx / Wb, tw = gx - fullb * Wb;
    int bx, by;
    if (id < fullb * Wb * gy) {
        int band = id / (Wb * gy), wi = id % (Wb * gy);
        bx = band * Wb + wi % Wb;
        by = wi / Wb;
    } else {
        int wi = id - fullb * Wb * gy;
        bx = fullb * Wb + wi % tw;
        by = wi / tw;
    }
    const int bm = by * 128;
    const int bn = bx * 128;

    const int r    = tid >> 1;
    const int kq   = (tid & 1) * 16;
    const int arow = min(bm + r, M - 1);
    const bf16* ga = A  + (size_t)arow * lda + kq;
    const bf16* gb = Bw + (size_t)(bn + r) * ldb + kq;
    const int wm = (w >> 1) * 64;
    const int wn = (w & 1) * 64;
    const int lr = lane & 15;
    const int lk = (lane >> 4) * 8;

    f32x4 acc[4][4] = {};

    for (int k0 = 0; k0 < K; k0 += 32) {
        bf16x8 va0 = *(const bf16x8*)(ga + k0);
        bf16x8 va1 = *(const bf16x8*)(ga + k0 + 8);
        bf16x8 vb0 = *(const bf16x8*)(gb + k0);
        bf16x8 vb1 = *(const bf16x8*)(gb + k0 + 8);
        __syncthreads();
        *(bf16x8*)&As[r * 40 + kq]     = va0;
        *(bf16x8*)&As[r * 40 + kq + 8] = va1;
        *(bf16x8*)&Bs[r * 40 + kq]     = vb0;
        *(bf16x8*)&Bs[r * 40 + kq + 8] = vb1;
        __syncthreads();
        bf16x8 af[4], bfv[4];
#pragma unroll
        for (int mi = 0; mi < 4; ++mi)
            af[mi] = *(const bf16x8*)&As[(wm + mi * 16 + lr) * 40 + lk];
#pragma unroll
        for (int ni = 0; ni < 4; ++ni)
            bfv[ni] = *(const bf16x8*)&Bs[(wn + ni * 16 + lr) * 40 + lk];
#pragma unroll
        for (int mi = 0; mi < 4; ++mi)
#pragma unroll
            for (int ni = 0; ni < 4; ++ni)
                acc[mi][ni] = __builtin_amdgcn_mfma_f32_16x16x32_bf16(
                    af[mi], bfv[ni], acc[mi][ni], 0, 0, 0);
    }

#pragma unroll
    for (int mi = 0; mi < 4; ++mi)
#pragma unroll
        for (int ni = 0; ni < 4; ++ni) {
            int n = bn + wn + ni * 16 + lr;
            if (n >= Nout) continue;
            float bv = bias[n];
#pragma unroll
            for (int rr = 0; rr < 4; ++rr) {
                int m = bm + wm + mi * 16 + (lane >> 4) * 4 + rr;
                if (m < M) {
                    float v = clampdiag(acc[mi][ni][rr] + bv);
                    size_t idx = (size_t)m * ldc + n;
                    if (outMode == 0)      ((float*)Cp)[idx] = v;
                    else if (outMode == 1) ((bf16*)Cp)[idx] = (bf16)v;
                    else {
                        if (f32w) ((float*)Cp)[idx] = v;
                        else      ((bf16*)Cp)[idx] = (bf16)v;
                    }
                }
            }
        }
}

// ---------------------------------------------------------------------------
// Grid barrier: plain atomic arrival + non-serializing sc0sc1 load poll.
// ---------------------------------------------------------------------------
__device__ __forceinline__ void gridbar(int* ctr, int target)
{
    __syncthreads();
    if (threadIdx.x == 0) {
        atomicAdd(ctr, 1);
        int v;
        do {
            asm volatile("global_load_dword %0, %1, off sc0 sc1\n\t"
                         "s_waitcnt vmcnt(0)"
                         : "=v"(v) : "v"(ctr) : "memory");
        } while (v < target);
    }
    __syncthreads();
    asm volatile("" ::: "memory");
}

// ---------------------------------------------------------------------------
// Persistent per-layer LSTM, v3:
//  * 72 blocks x 256 thr (4 waves, 1 block/CU, __launch_bounds__(256,1) ->
//    512-VGPR budget).
//  * Whh B-fragments PERSISTENT IN REGISTERS (144 VGPR/wave) — no Wl LDS.
//  * K split 4 ways (9 kt each): H read ONCE per block (184KB, was 737KB),
//    per-mi double-buffered A loads.
//  * Cross-wave reduce: one b128 write per (s,mi) per wave; same-lane b128
//    reads by consumer. All 64 lanes consume a 16-row quintile (wave0: 2).
//  * c in registers, G(t+1) prefetched, sc1 H-stores, fence-free barrier.
// ---------------------------------------------------------------------------
template<typename GT>
__global__ __launch_bounds__(256, 1)
void lstm_layer(const bf16* __restrict__ Whh,   // [4608][1152] padded
                const GT* __restrict__ G,       // [70][80][N4P]
                const bf16* __restrict__ H0,    // [80][KH]
                float* __restrict__ Cst,        // [80][KH]
                bf16* __restrict__ HA,          // [70][80][KH]
                int* __restrict__ ctr)
{
    __shared__ __align__(16) float pl4[4][4][5][64][4];   // [w][s][mi][lane][4] = 80KB
    const int tid  = threadIdx.x;
    const int lane = tid & 63;
    const int w    = tid >> 6;          // 0..3 = K-slice
    const int q    = lane >> 4;
    const int lr   = lane & 15;
    const int n0   = blockIdx.x * 16;
    const int jc   = n0 + lr;
    const bool jok = (jc < HIDD);
    const int jrow = jok ? jc : (HIDD - 1);

    // ---- persistent B fragments: this wave's 9 kt x 4 gates ----
    bf16x8 bfr[4][9];
#pragma unroll
    for (int s = 0; s < 4; ++s)
#pragma unroll
        for (int k = 0; k < 9; ++k)
            bfr[s][k] = *(const bf16x8*)(Whh + (size_t)(s * HIDD + jrow) * KH
                                          + (w * 9 + k) * 32 + q * 8);

    const int QA = w;
    const bool hasB = (w == 0);
    const int QB = 4;

    float cregA[4], cregB[4];
#pragma unroll
    for (int rr = 0; rr < 4; ++rr) {
        cregA[rr] = jok ? Cst[(size_t)(QA * 16 + q * 4 + rr) * KH + jc] : 0.f;
        cregB[rr] = (hasB && jok) ? Cst[(size_t)(QB * 16 + q * 4 + rr) * KH + jc] : 0.f;
    }

    float gpA[16], gpB[16], gnA[16], gnB[16];
#pragma unroll
    for (int s = 0; s < 4; ++s)
#pragma unroll
        for (int rr = 0; rr < 4; ++rr) {
            gpA[s * 4 + rr] = jok ? (float)G[(size_t)(QA * 16 + q * 4 + rr) * N4P + s * HIDD + jc] : 0.f;
            gpB[s * 4 + rr] = (hasB && jok) ? (float)G[(size_t)(QB * 16 + q * 4 + rr) * N4P + s * HIDD + jc] : 0.f;
        }

    for (int t = 0; t < SEQL; ++t) {
        const bf16* Hin = t ? (HA + (size_t)(t - 1) * BAT * KH) : H0;
        bf16*       HAt = HA + (size_t)t * BAT * KH;

        // ---- G(t+1) prefetch (immutable; crosses barriers safely) ----
        if (t + 1 < SEQL) {
            const GT* g1 = G + (size_t)(t + 1) * BAT * N4P;
#pragma unroll
            for (int s = 0; s < 4; ++s)
#pragma unroll
                for (int rr = 0; rr < 4; ++rr) {
                    gnA[s * 4 + rr] = jok ? (float)g1[(size_t)(QA * 16 + q * 4 + rr) * N4P + s * HIDD + jc] : 0.f;
                    gnB[s * 4 + rr] = (hasB && jok) ? (float)g1[(size_t)(QB * 16 + q * 4 + rr) * N4P + s * HIDD + jc] : 0.f;
                }
        }

        // ---- MFMA phase: K-slice [w*288, w*288+288), double-buffered A ----
        const bf16* hb = Hin + (w * 9) * 32 + q * 8;
        f32x4 acc[4][5] = {};
        bf16x8 a0[9], a1[9];
#pragma unroll
        for (int k = 0; k < 9; ++k)
            a0[k] = *(const bf16x8*)(hb + (size_t)(lr) * KH + k * 32);
#pragma unroll
        for (int mi = 0; mi < 5; ++mi) {
            if (mi < 4) {
#pragma unroll
                for (int k = 0; k < 9; ++k) {
                    bf16x8 v = *(const bf16x8*)(hb + (size_t)((mi + 1) * 16 + lr) * KH + k * 32);
                    if (mi & 1) a0[k] = v; else a1[k] = v;
                }
            }
#pragma unroll
            for (int k = 0; k < 9; ++k) {
                bf16x8 av = (mi & 1) ? a1[k] : a0[k];
#pragma unroll
                for (int s = 0; s < 4; ++s)
                    acc[s][mi] = __builtin_amdgcn_mfma_f32_16x16x32_bf16(
                        av, bfr[s][k], acc[s][mi], 0, 0, 0);
            }
        }

        // ---- cross-wave K-reduction: one b128 per (s,mi) ----
#pragma unroll
        for (int s = 0; s < 4; ++s)
#pragma unroll
            for (int mi = 0; mi < 5; ++mi)
                *(f32x4*)&pl4[w][s][mi][lane][0] = acc[s][mi];
        __syncthreads();

        // ---- consumer: quintile QA (all waves) + QB (wave 0) ----
        {
            f32x4 p[4];
#pragma unroll
            for (int s = 0; s < 4; ++s)
                p[s] = *(const f32x4*)&pl4[0][s][QA][lane][0]
                     + *(const f32x4*)&pl4[1][s][QA][lane][0]
                     + *(const f32x4*)&pl4[2][s][QA][lane][0]
                     + *(const f32x4*)&pl4[3][s][QA][lane][0];
            if (jok) {
#pragma unroll
                for (int rr = 0; rr < 4; ++rr) {
                    float pi = p[0][rr] + gpA[0 + rr];
                    float pf = p[1][rr] + gpA[4 + rr];
                    float po = p[2][rr] + gpA[8 + rr];
                    float pg = p[3][rr] + gpA[12 + rr];
                    float ii = 1.f / (1.f + expf(-pi));
                    float ff = 1.f / (1.f + expf(-pf));
                    float oo = 1.f / (1.f + expf(-po));
                    float gg = tanhf(pg);
                    float cn = ff * cregA[rr] + ii * gg;
                    cregA[rr] = cn;
                    bf16 hv = (bf16)(oo * tanhf(cn));
                    store_h_sc1(HAt + (size_t)(QA * 16 + q * 4 + rr) * KH + jc,
                                (uint32_t)__builtin_bit_cast(unsigned short, hv));
                }
            }
        }
        if (hasB) {
            f32x4 p[4];
#pragma unroll
            for (int s = 0; s < 4; ++s)
                p[s] = *(const f32x4*)&pl4[0][s][QB][lane][0]
                     + *(const f32x4*)&pl4[1][s][QB][lane][0]
                     + *(const f32x4*)&pl4[2][s][QB][lane][0]
                     + *(const f32x4*)&pl4[3][s][QB][lane][0];
            if (jok) {
#pragma unroll
                for (int rr = 0; rr < 4; ++rr) {
                    float pi = p[0][rr] + gpB[0 + rr];
                    float pf = p[1][rr] + gpB[4 + rr];
                    float po = p[2][rr] + gpB[8 + rr];
                    float pg = p[3][rr] + gpB[12 + rr];
                    float ii = 1.f / (1.f + expf(-pi));
                    float ff = 1.f / (1.f + expf(-pf));
                    float oo = 1.f / (1.f + expf(-po));
                    float gg = tanhf(pg);
                    float cn = ff * cregB[rr] + ii * gg;
                    cregB[rr] = cn;
                    bf16 hv = (bf16)(oo * tanhf(cn));
                    store_h_sc1(HAt + (size_t)(QB * 16 + q * 4 + rr) * KH + jc,
                                (uint32_t)__builtin_bit_cast(unsigned short, hv));
                }
            }
        }

        if (t < SEQL - 1) {
            asm volatile("s_waitcnt vmcnt(0)" ::: "memory");  // sc1 stores at L3
            gridbar(ctr, NBLK * (t + 1));
#pragma unroll
            for (int i = 0; i < 16; ++i) { gpA[i] = gnA[i]; gpB[i] = gnB[i]; }
        }
    }

    // ---- final c writeback ----
    if (jok) {
#pragma unroll
        for (int rr = 0; rr < 4; ++rr)
            Cst[(size_t)(QA * 16 + q * 4 + rr) * KH + jc] = cregA[rr];
        if (hasB) {
#pragma unroll
            for (int rr = 0; rr < 4; ++rr)
                Cst[(size_t)(QB * 16 + q * 4 + rr) * KH + jc] = cregB[rr];
        }
    }
}

__global__ void bar_reset(int* ctr) { if (threadIdx.x == 0) *ctr = 0; }

// ---------------------------------------------------------------------------
// Prep kernels (dual-dtype via dflag) — unchanged.
// ---------------------------------------------------------------------------
__global__ void pad_weight(const void* __restrict__ src, int N, int K,
                           bf16* __restrict__ dst, int Np, int Kp,
                           const int* __restrict__ dflag)
{
    const int f32w = *dflag;
    size_t total = (size_t)Np * Kp;
    for (size_t i = (size_t)blockIdx.x * blockDim.x + threadIdx.x; i < total;
         i += (size_t)gridDim.x * blockDim.x) {
        int n = (int)(i / Kp), k = (int)(i % Kp);
        dst[i] = (n < N && k < K) ? (bf16)ld_in(src, (size_t)n * K + k, f32w)
                                  : (bf16)0.f;
    }
}

__global__ void combine_bias(const void* a, const void* b, float* o, int n, int np,
                             const int* __restrict__ dflag)
{
    const int f32w = *dflag;
    int i = blockIdx.x * blockDim.x + threadIdx.x;
    if (i < np) o[i] = (i < n) ? ld_in(a, i, f32w) + ld_in(b, i, f32w) : 0.f;
}

__global__ void cvt_bias(const void* a, float* o, int n, int np,
                         const int* __restrict__ dflag)
{
    const int f32w = *dflag;
    int i = blockIdx.x * blockDim.x + threadIdx.x;
    if (i < np) o[i] = (i < n) ? ld_in(a, i, f32w) : 0.f;
}

__global__ void embed_gather(const int* __restrict__ x, const void* __restrict__ emb,
                             bf16* __restrict__ XE, const int* __restrict__ dflag)
{
    const int f32w = *dflag;
    int row = blockIdx.x;
    int xi  = x[row];
    for (int e = threadIdx.x; e < KE; e += blockDim.x)
        XE[(size_t)row * KE + e] =
            (e < EMBD) ? (bf16)ld_in(emb, (size_t)xi * EMBD + e, f32w) : (bf16)0.f;
}

__global__ void zero_ha_pad(bf16* HA)
{
    int i = blockIdx.x * blockDim.x + threadIdx.x;
    if (i < MALL * 2) HA[(size_t)(i >> 1) * KH + HIDD + (i & 1)] = (bf16)0.f;
}

__global__ void init_state(const void* __restrict__ h0, const void* __restrict__ c0,
                           size_t lofs, bf16* Hb0, float* Cst,
                           const int* __restrict__ dflag)
{
    const int f32w = *dflag;
    int i = blockIdx.x * blockDim.x + threadIdx.x;
    if (i >= BAT * KH) return;
    int b = i / KH, j = i % KH;
    if (j < HIDD) {
        Hb0[i] = (bf16)ld_in(h0, lofs + (size_t)b * HIDD + j, f32w);
        Cst[i] = ld_in(c0, lofs + (size_t)b * HIDD + j, f32w);
    } else {
        Hb0[i] = (bf16)0.f;
        Cst[i] = 0.f;
    }
}

__global__ void write_tail(const bf16* __restrict__ Hfin, const float* __restrict__ Cfin,
                           void* __restrict__ outBase, size_t hOfs, size_t cOfs,
                           const int* __restrict__ dflag)
{
    const int f32w = *dflag;
    int i = blockIdx.x * blockDim.x + threadIdx.x;
    if (i >= BAT * HIDD) return;
    int b = i / HIDD, j = i % HIDD;
    float hv = clampdiag((float)Hfin[b * KH + j]);
    float cv = clampdiag(Cfin[b * KH + j]);
    if (f32w) {
        ((float*)outBase)[hOfs + i] = hv;
        ((float*)outBase)[cOfs + i] = cv;
    } else {
        ((bf16*)outBase)[hOfs + i] = (bf16)hv;
        ((bf16*)outBase)[cOfs + i] = (bf16)cv;
    }
}

__global__ void sentinel_kernel(void* out, float v, const int* __restrict__ dflag)
{
    if (blockIdx.x == 0 && threadIdx.x == 0) {
        if (*dflag) ((float*)out)[0] = v;
        else        ((bf16*)out)[0] = (bf16)v;
    }
}

// ---------------------------------------------------------------------------
extern "C" void kernel_launch(void* const* d_in, const int* in_sizes, int n_in,
                              void* d_out, int out_size, void* d_ws, size_t ws_size,
                              hipStream_t stream)
{
    const int*  x    = (const int*)d_in[0];
    const void* h0   = d_in[1];
    const void* c0   = d_in[2];
    const void* emb  = d_in[3];
    const void* wih[3] = {d_in[4], d_in[8],  d_in[12]};
    const void* bih[3] = {d_in[5], d_in[9],  d_in[13]};
    const void* whh[3] = {d_in[6], d_in[10], d_in[14]};
    const void* bhh[3] = {d_in[7], d_in[11], d_in[15]};
    const void* wdec = d_in[16];
    const void* bdec = d_in[17];
    const size_t DEC = (size_t)MALL * NTOKV;
    (void)in_sizes; (void)n_in; (void)out_size;

    auto al = [](size_t v) { return (v + 255) & ~(size_t)255; };
    const size_t wdecB = al((size_t)NVP * KH * 2);
    auto plan = [&](bool gbf, size_t* offs) -> size_t {
        size_t off = 0;
        auto carve = [&](size_t b) { size_t p = off; off += al(b); return p; };
        offs[0] = carve((size_t)MALL * N4P * (gbf ? 2 : 4));
        offs[1] = carve((size_t)MALL * KE * 2);
        offs[2] = carve((size_t)N4P * KH * 2);
        offs[3] = carve((size_t)N4P * KH * 2);
        if (off < wdecB) off = wdecB;
        offs[4] = carve((size_t)MALL * KH * 2);
        offs[5] = carve((size_t)N4P * 4);
        offs[6] = carve((size_t)NVP * 4);
        offs[7] = carve((size_t)BAT * KH * 2);
        offs[8] = carve((size_t)BAT * KH * 4);
        offs[9] = carve(256);
        return off;
    };
    size_t offs[10];
    size_t needA = plan(false, offs);
    size_t needB = plan(true, offs);
    bool gbf16;
    if (ws_size >= needA)      { gbf16 = false; plan(false, offs); }
    else if (ws_size >= needB) { gbf16 = true;  plan(true,  offs); }
    else {
        int* dflag = (int*)d_ws;
        detect_dtype<<<1, 256, 0, stream>>>(emb, dflag);
        float mb = (float)(ws_size >> 20);
        if (mb > 20000.f) mb = 20000.f;
        sentinel_kernel<<<1, 64, 0, stream>>>(d_out, 700.f + mb, dflag);
        return;
    }

    char* ws = (char*)d_ws;
    void* G      = ws + offs[0];
    bf16* XE     = (bf16*)(ws + offs[1]);
    bf16* WihP   = (bf16*)(ws + offs[2]);
    bf16* WhhP   = (bf16*)(ws + offs[3]);
    bf16* WdecP  = (bf16*)(ws + 0);
    bf16* HA     = (bf16*)(ws + offs[4]);
    float* bc    = (float*)(ws + offs[5]);
    float* bd    = (float*)(ws + offs[6]);
    bf16* H0buf  = (bf16*)(ws + offs[7]);
    float* Cst   = (float*)(ws + offs[8]);
    int*  dflag  = (int*)(ws + offs[9]);
    int*  barctr = (int*)(ws + offs[9] + 128);

    detect_dtype<<<1, 256, 0, stream>>>(emb, dflag);
    embed_gather<<<MALL, 128, 0, stream>>>(x, emb, XE, dflag);
    zero_ha_pad<<<(MALL * 2 + 255) / 256, 256, 0, stream>>>(HA);

    for (int l = 0; l < 3; ++l) {
        int kin = (l == 0) ? KE : KH;
        int Kin = (l == 0) ? EMBD : HIDD;
        pad_weight<<<2048, 256, 0, stream>>>(wih[l], GATES, Kin, WihP, N4P, kin, dflag);
        pad_weight<<<2048, 256, 0, stream>>>(whh[l], GATES, HIDD, WhhP, N4P, KH, dflag);
        combine_bias<<<(N4P + 255) / 256, 256, 0, stream>>>(bih[l], bhh[l], bc, GATES, N4P, dflag);
        init_state<<<(BAT * KH + 255) / 256, 256, 0, stream>>>(
            h0, c0, (size_t)l * BAT * HIDD, H0buf, Cst, dflag);
        bar_reset<<<1, 64, 0, stream>>>(barctr);
        const bf16* Ain = (l == 0) ? XE : HA;
        {
            int gx = N4P / 128, gy = (MALL + 127) / 128;
            gemm_bt<<<gx * gy, 256, 0, stream>>>(
                Ain, kin, WihP, kin, bc, G, N4P, MALL, kin, N4P,
                gbf16 ? 1 : 0, dflag, gx, gy);
        }
        if (gbf16)
            lstm_layer<bf16><<<NBLK, 256, 0, stream>>>(
                WhhP, (const bf16*)G, H0buf, Cst, HA, barctr);
        else
            lstm_layer<float><<<NBLK, 256, 0, stream>>>(
                WhhP, (const float*)G, H0buf, Cst, HA, barctr);
        write_tail<<<(BAT * HIDD + 255) / 256, 256, 0, stream>>>(
            HA + (size_t)(SEQL - 1) * BAT * KH, Cst, d_out,
            DEC + (size_t)l * BAT * HIDD,
            DEC + (size_t)3 * BAT * HIDD + (size_t)l * BAT * HIDD, dflag);
    }

    pad_weight<<<4096, 256, 0, stream>>>(wdec, NTOKV, HIDD, WdecP, NVP, KH, dflag);
    cvt_bias<<<(NVP + 255) / 256, 256, 0, stream>>>(bdec, bd, NTOKV, NVP, dflag);
    {
        int gx = NVP / 128, gy = (MALL + 127) / 128;
        gemm_bt<<<gx * gy, 256, 0, stream>>>(
            HA, KH, WdecP, KH, bd, d_out, NTOKV, MALL, KH, NTOKV, 2, dflag, gx, gy);
    }
}